// Round 9
// baseline (410.713 us; speedup 1.0000x reference)
//
#include <hip/hip_runtime.h>
#include <cstdint>
#include <cstddef>
#include <cmath>

typedef __bf16 bf16x8 __attribute__((ext_vector_type(8)));
typedef float  f32x4  __attribute__((ext_vector_type(4)));

__device__ __forceinline__ unsigned short f2bf(float f) {
  unsigned int u = __float_as_uint(f);
  u += 0x7FFF + ((u >> 16) & 1);
  return (unsigned short)(u >> 16);
}
__device__ __forceinline__ float bf2f(unsigned short u) {
  return __uint_as_float(((unsigned int)u) << 16);
}

#define SEQ 2048
#define DMODEL 2048
#define NH 16
#define HD 128
#define NB 2
#define NP 10
#define MAUG 4106
#define SCALEL2 (0.08838834764831845f * 1.44269504088896340f)

#define GLOAD_LDS16(g, l) \
  __builtin_amdgcn_global_load_lds((__attribute__((address_space(1))) const void*)(g), \
                                   (__attribute__((address_space(3))) void*)(l), 16, 0, 0)

#define FENCE() asm volatile("" ::: "memory")
#define SBAR() do { FENCE(); __builtin_amdgcn_s_barrier(); FENCE(); } while (0)
#define WAITVM(N) asm volatile("s_waitcnt vmcnt(" #N ")" ::: "memory")

// ---------- 1+2+3 fused preprocessing: tables | weight transpose | x-aug ----------
__global__ __launch_bounds__(256) void k_prep(const float* __restrict__ W0,
                                              const float* __restrict__ W1,
                                              const float* __restrict__ W2,
                                              const float* __restrict__ W3,
                                              const float* __restrict__ X,
                                              const float* __restrict__ Aq,
                                              unsigned short* __restrict__ wt,
                                              unsigned short* __restrict__ xaug,
                                              float* __restrict__ cost,
                                              float* __restrict__ sint) {
  __shared__ float tile[64][65];   // pad 65: transposed reads 2-way (free)
  const int bid = blockIdx.x;
  const int t = threadIdx.x;
  if (bid < 512) {
    // ---- RoPE tables (f32; reference computes in f32, tol 1.5e-2) ----
    int idx = bid * 256 + t;
    int s = idx >> 6, i = idx & 63;
    float invf = expf(-((float)(2 * i) / 128.0f) * logf(10000.0f));
    float a = (float)s * invf;
    float c = cosf(a), sn = sinf(a);
    cost[s * HD + i] = c;  cost[s * HD + 64 + i] = c;
    sint[s * HD + i] = sn; sint[s * HD + 64 + i] = sn;
  } else if (bid < 512 + 4096) {
    // ---- weight transpose + cast: 64x64 tiles ----
    int wi = bid - 512;
    int zw = wi >> 10, rem = wi & 1023;
    const float* W = (zw == 0) ? W0 : (zw == 1) ? W1 : (zw == 2) ? W2 : W3;
    unsigned short* o = wt + (size_t)zw * DMODEL * DMODEL;
    int bx = (rem & 31) * 64, by = (rem >> 5) * 64;
    int c = t & 15, r0 = t >> 4;
    #pragma unroll
    for (int jj = 0; jj < 4; jj++) {
      int r = r0 + jj * 16;
      float4 v = *(const float4*)&W[(size_t)(bx + r) * DMODEL + by + c * 4];
      tile[r][c * 4 + 0] = v.x; tile[r][c * 4 + 1] = v.y;
      tile[r][c * 4 + 2] = v.z; tile[r][c * 4 + 3] = v.w;
    }
    __syncthreads();
    #pragma unroll
    for (int jj = 0; jj < 4; jj++) {
      int ro = r0 + jj * 16;
      unsigned short s4[4];
      #pragma unroll
      for (int k = 0; k < 4; k++) s4[k] = f2bf(tile[c * 4 + k][ro]);
      *(uint2*)&o[(size_t)(by + ro) * DMODEL + bx + c * 4] = *(const uint2*)s4;
    }
  } else {
    // ---- X augmented + cast: 8 elems/thread ----
    int xi = bid - 4608;
    size_t u = ((size_t)xi * 256 + t) * 8;
    size_t row = u >> 11;
    int col = (int)(u & 2047);
    const float* src = (row < (size_t)NB * SEQ) ? &X[u]
                                                : &Aq[(row - NB * SEQ) * DMODEL + col];
    float4 a = *(const float4*)src;
    float4 b = *(const float4*)(src + 4);
    unsigned short r[8] = { f2bf(a.x), f2bf(a.y), f2bf(a.z), f2bf(a.w),
                            f2bf(b.x), f2bf(b.y), f2bf(b.z), f2bf(b.w) };
    *(uint4*)&xaug[u] = *(const uint4*)r;
  }
}

// ---------- 4a. MFMA GEMM: 256x256, BK=32, quad-buffered, 1 wait + 1 barrier / K-tile ----------
// Deep prefetch: tile t+3 staged during tile t -> every WAITVM(8) is pre-satisfied
// (loads land ~2 tiles ~ 4000 cyc before use; vmcnt never drains in main loop).
// Swizzle: LDS granule slot s of row holds global k-granule s ^ ((row>>1)&3)
// (8 consecutive rows hit all 8 128B-line slots -> 2-way bank access = free).
#define G_RD() do { \
  _Pragma("unroll") for (int mi_ = 0; mi_ < 8; mi_++) \
    a[mi_] = *(const bf16x8*)&lds[bb + (wr*128 + mi_*16 + lr)*32 + rsw8]; \
  _Pragma("unroll") for (int nj_ = 0; nj_ < 4; nj_++) \
    b[nj_] = *(const bf16x8*)&lds[bb + 8192 + (wc*64 + nj_*16 + lr)*32 + rsw8]; \
} while (0)

#define G_STG(bufi, ko) do { \
  GLOAD_LDS16(sA + (ko),                      &lds[(bufi)*16384 + t*8]); \
  GLOAD_LDS16(sA + 128*(size_t)DMODEL + (ko), &lds[(bufi)*16384 + 4096 + t*8]); \
  GLOAD_LDS16(sB + (ko),                      &lds[(bufi)*16384 + 8192 + t*8]); \
  GLOAD_LDS16(sB + 128*(size_t)DMODEL + (ko), &lds[(bufi)*16384 + 12288 + t*8]); \
} while (0)

template<int BF16OUT>
__global__ __launch_bounds__(512, 2) void k_gemm256(const unsigned short* __restrict__ A,
                                                    const unsigned short* __restrict__ Bt,
                                                    void* __restrict__ Cv,
                                                    int M, size_t c_stride_mat) {
  __shared__ unsigned short lds[65536];   // 128 KiB: 4 bufs x [A 256x32 | B 256x32]
  const int t = threadIdx.x;
  const int lane = t & 63, w = t >> 6;
  const int lr = lane & 15, quad = lane >> 4;
  const int wr = w >> 2, wc = w & 3;       // 2x4 wave grid; per-wave 128x64 output
  const int rsw8 = (quad ^ ((lr >> 1) & 3)) * 8;
  // XCD-aware bijective swizzle (gridDim.x % 8 == 0)
  const int tm = (M + 255) >> 8;
  const int perz = tm * 8;
  const int qchunk = gridDim.x >> 3;
  const int lin = ((int)blockIdx.x & 7) * qchunk + ((int)blockIdx.x >> 3);
  const int z = lin / perz;
  const int rem = lin - z * perz;
  const int m0 = (rem >> 3) * 256, n0 = (rem & 7) * 256;
  const unsigned short* Bz = Bt + (size_t)z * DMODEL * DMODEL;

  // staging: thread t -> row t>>2, granule t&3; source granule inverse-swizzled
  const int srow = t >> 2;
  const int scol8 = ((t & 3) ^ ((t >> 3) & 3)) * 8;
  const unsigned short* sA = A + (size_t)(m0 + srow) * DMODEL + scol8;
  const unsigned short* sB = Bz + (size_t)(n0 + srow) * DMODEL + scol8;

  bf16x8 a[8], b[4];
  f32x4 acc[8][4];
  #pragma unroll
  for (int i = 0; i < 8; i++)
    #pragma unroll
    for (int j = 0; j < 4; j++) acc[i][j] = (f32x4){0.f, 0.f, 0.f, 0.f};

  // prologue: stage tiles 0,1,2 (12 loads); drain tile 0 (keep 8 in flight)
  G_STG(0, 0); G_STG(1, 32); G_STG(2, 64);
  WAITVM(8);
  SBAR();

  for (int kt = 0; kt < 64; kt++) {
    const int bb = (kt & 3) * 16384;
    G_RD();
    if (kt < 61) G_STG((kt + 3) & 3, (kt + 3) * 32);
    __builtin_amdgcn_s_setprio(1);
    #pragma unroll
    for (int mi = 0; mi < 8; mi++)
      #pragma unroll
      for (int nj = 0; nj < 4; nj++)
        acc[mi][nj] = __builtin_amdgcn_mfma_f32_16x16x32_bf16(a[mi], b[nj], acc[mi][nj], 0, 0, 0);
    __builtin_amdgcn_s_setprio(0);
    if (kt < 63) {
      if (kt < 61) WAITVM(8);        // drains tile kt+1's 4 loads (issued at kt-2)
      else if (kt == 61) WAITVM(4);  // tail: only t62,t63 outstanding
      else WAITVM(0);
      SBAR();
    }
  }

  #pragma unroll
  for (int mi = 0; mi < 8; mi++) {
    #pragma unroll
    for (int r = 0; r < 4; r++) {
      int row = m0 + wr * 128 + mi * 16 + quad * 4 + r;
      if (row < M) {
        if (BF16OUT) {
          unsigned short* C = (unsigned short*)Cv + (size_t)z * c_stride_mat;
          #pragma unroll
          for (int n = 0; n < 4; n++)
            C[(size_t)row * DMODEL + n0 + wc * 64 + n * 16 + lr] = f2bf(acc[mi][n][r]);
        } else {
          float* C = (float*)Cv + (size_t)z * c_stride_mat;
          #pragma unroll
          for (int n = 0; n < 4; n++)
            C[(size_t)row * DMODEL + n0 + wc * 64 + n * 16 + lr] = acc[mi][n][r];
        }
      }
    }
  }
}

// ---------- 4b. out-proj GEMM: 128x256 tile, grid 256 blocks, XCD-swizzled (R3 best) ----------
#define O_LDA(MH) do { \
  _Pragma("unroll") for (int i_ = 0; i_ < 2; i_++) \
    _Pragma("unroll") for (int ks_ = 0; ks_ < 2; ks_++) \
      a[i_][ks_] = *(const bf16x8*)&lds[base + (wr*64 + ((MH)*2+i_)*16 + lr)*64 + (((ks_*4+quad) ^ (lr & 7)) * 8)]; \
} while (0)

#define O_LDB(NHH) do { \
  _Pragma("unroll") for (int j_ = 0; j_ < 2; j_++) \
    _Pragma("unroll") for (int ks_ = 0; ks_ < 2; ks_++) \
      b[(NHH)*2+j_][ks_] = *(const bf16x8*)&lds[base + 8192 + (wc*64 + ((NHH)*2+j_)*16 + lr)*64 + (((ks_*4+quad) ^ (lr & 7)) * 8)]; \
} while (0)

#define O_MFMA(MH, NHH) do { \
  __builtin_amdgcn_s_setprio(1); \
  _Pragma("unroll") for (int i_ = 0; i_ < 2; i_++) \
    _Pragma("unroll") for (int j_ = 0; j_ < 2; j_++) { \
      acc[(MH)*2+i_][(NHH)*2+j_] = __builtin_amdgcn_mfma_f32_16x16x32_bf16(a[i_][0], b[(NHH)*2+j_][0], acc[(MH)*2+i_][(NHH)*2+j_], 0, 0, 0); \
      acc[(MH)*2+i_][(NHH)*2+j_] = __builtin_amdgcn_mfma_f32_16x16x32_bf16(a[i_][1], b[(NHH)*2+j_][1], acc[(MH)*2+i_][(NHH)*2+j_], 0, 0, 0); \
    } \
  __builtin_amdgcn_s_setprio(0); \
} while (0)

#define O_STG_AE(nb, ko) GLOAD_LDS16(sA + (ko), &lds[(nb)*24576 + (qb)*64 + g8])
#define O_STG_AO(nb, ko) GLOAD_LDS16(sA + 32*(size_t)DMODEL + (ko), &lds[(nb)*24576 + (32+qb)*64 + g8])
#define O_STG_BE(nb, ko) do { \
  GLOAD_LDS16(sB + (ko),                      &lds[(nb)*24576 + 8192 + (qb)*64 + g8]); \
  GLOAD_LDS16(sB + 128*(size_t)DMODEL + (ko), &lds[(nb)*24576 + 8192 + (128+qb)*64 + g8]); } while (0)
#define O_STG_BO(nb, ko) do { \
  GLOAD_LDS16(sB + 32*(size_t)DMODEL + (ko),  &lds[(nb)*24576 + 8192 + (32+qb)*64 + g8]); \
  GLOAD_LDS16(sB + 160*(size_t)DMODEL + (ko), &lds[(nb)*24576 + 8192 + (160+qb)*64 + g8]); } while (0)

__global__ __launch_bounds__(512, 2) void k_gemmo(const unsigned short* __restrict__ A,
                                                  const unsigned short* __restrict__ Bt,
                                                  float* __restrict__ C) {
  __shared__ unsigned short lds[49152];   // 96 KiB: [2 bufs][A 128x64 | B 256x64]
  const int t = threadIdx.x;
  const int lane = t & 63, w = t >> 6;
  const int lr = lane & 15, quad = lane >> 4;
  const int wr = w >> 2, wc = w & 3;
  const int lin = ((int)blockIdx.x & 7) * 32 + ((int)blockIdx.x >> 3);
  const int m0 = (lin >> 3) * 128, n0 = (lin & 7) * 256;

  const int qrow = t >> 3;
  const int g8 = (t & 7) * 8;
  const int gsw8 = (((t & 7) ^ (qrow & 7)) * 8);
  const int qb = (qrow < 32) ? qrow : qrow + 32;

  const unsigned short* sA = A + (size_t)(m0 + qb) * DMODEL + gsw8;
  const unsigned short* sB = Bt + (size_t)(n0 + qb) * DMODEL + gsw8;

  bf16x8 a[2][2], b[4][2];
  f32x4 acc[4][4];
  #pragma unroll
  for (int i = 0; i < 4; i++)
    #pragma unroll
    for (int j = 0; j < 4; j++) acc[i][j] = (f32x4){0.f, 0.f, 0.f, 0.f};

  O_STG_AE(0, 0); O_STG_BE(0, 0); O_STG_BO(0, 0); O_STG_AO(0, 0);
  WAITVM(3);
  SBAR();

  for (int kt = 0; kt < DMODEL / 64; kt++) {
    const int base = (kt & 1) * 24576;
    const int nb = (kt & 1) ^ 1;
    const int ko = (kt + 1) * 64;
    const bool more = (kt + 1 < DMODEL / 64);

    O_LDA(0);
    O_LDB(0);
    if (more) O_STG_AE(nb, ko);
    SBAR();
    O_MFMA(0, 0);
    if (more) WAITVM(2); else WAITVM(1);
    SBAR();

    O_LDB(1);
    if (more) O_STG_BE(nb, ko);
    SBAR();
    O_MFMA(0, 1);
    if (more) WAITVM(3); else WAITVM(0);
    SBAR();

    O_LDA(1);
    if (more) O_STG_BO(nb, ko);
    SBAR();
    O_MFMA(1, 0);
    SBAR();

    if (more) O_STG_AO(nb, ko);
    SBAR();
    O_MFMA(1, 1);
    if (more) WAITVM(3);
    SBAR();
  }

  #pragma unroll
  for (int mi = 0; mi < 4; mi++) {
    #pragma unroll
    for (int r = 0; r < 4; r++) {
      int row = m0 + wr * 64 + mi * 16 + quad * 4 + r;
      #pragma unroll
      for (int n = 0; n < 4; n++)
        C[(size_t)row * DMODEL + n0 + wc * 64 + n * 16 + lr] = acc[mi][n][r];
    }
  }
}

// ---------- 5+6 fused: RoPE / adapter prep (blocks < MAUG) + V transpose (rest) ----------
__global__ __launch_bounds__(256) void k_ropevt(const unsigned short* __restrict__ Qf,
                                                const unsigned short* __restrict__ Kf,
                                                const unsigned short* __restrict__ Vf,
                                                const float* __restrict__ cost, const float* __restrict__ sint,
                                                unsigned short* __restrict__ Qb, unsigned short* __restrict__ Kb,
                                                unsigned short* __restrict__ AKb, unsigned short* __restrict__ avt,
                                                unsigned short* __restrict__ Vt) {
  __shared__ unsigned short tile[64][72];
  const int bid = blockIdx.x;
  const int t = threadIdx.x;
  if (bid < MAUG) {
    int row = bid;
    int c0 = t * 8;
    size_t off = (size_t)row * DMODEL + c0;
    if (row < NB * SEQ) {
      int s = row & (SEQ - 1);
      int d0 = c0 & (HD - 1);
      int po = (d0 < 64) ? 64 : -64;
      float sign = (d0 < 64) ? -1.f : 1.f;
      uint4 qv = *(const uint4*)&Qf[off];
      uint4 qp = *(const uint4*)&Qf[off + po];
      uint4 kv = *(const uint4*)&Kf[off];
      uint4 kp = *(const uint4*)&Kf[off + po];
      const unsigned short* qa = (const unsigned short*)&qv;
      const unsigned short* qb2 = (const unsigned short*)&qp;
      const unsigned short* ka = (const unsigned short*)&kv;
      const unsigned short* kb2 = (const unsigned short*)&kp;
      unsigned short oq[8], ok[8];
      #pragma unroll
      for (int j = 0; j < 8; j++) {
        float cv = cost[s * HD + d0 + j], sv = sint[s * HD + d0 + j];
        oq[j] = f2bf(bf2f(qa[j]) * cv + sign * bf2f(qb2[j]) * sv);
        ok[j] = f2bf(bf2f(ka[j]) * cv + sign * bf2f(kb2[j]) * sv);
      }
      *(uint4*)&Qb[off] = *(const uint4*)oq;
      *(uint4*)&Kb[off] = *(const uint4*)ok;
    } else {
      int p = row - NB * SEQ;
      uint4 kv = *(const uint4*)&Kf[off];
      uint4 vv = *(const uint4*)&Vf[off];
      *(uint4*)&AKb[(size_t)p * DMODEL + c0] = kv;
      const unsigned short* vp = (const unsigned short*)&vv;
      #pragma unroll
      for (int j = 0; j < 8; j++)
        avt[(size_t)(c0 + j) * 32 + p] = vp[j];
      if (p == 0) {
        #pragma unroll
        for (int j = 0; j < 8; j++)
          for (int pp = NP; pp < 32; pp++)
            avt[(size_t)(c0 + j) * 32 + pp] = 0;
      }
    }
  } else {
    int b2 = bid - MAUG;
    int s0 = (b2 & 31) * 64;
    int d0 = ((b2 >> 5) & 1) * 64;
    int z = b2 >> 6;
    int b = z >> 4, h = z & 15;
    #pragma unroll
    for (int j = t; j < 512; j += 256) {
      int row = j >> 3, ch = j & 7;
      *(uint4*)&tile[row][ch * 8] =
        *(const uint4*)&Vf[(size_t)(b * SEQ + s0 + row) * DMODEL + h * HD + d0 + ch * 8];
    }
    __syncthreads();
    #pragma unroll
    for (int j = t; j < 512; j += 256) {
      int dr = j >> 3, ch = j & 7;
      unsigned short tmp[8];
      #pragma unroll
      for (int k = 0; k < 8; k++) tmp[k] = tile[ch * 8 + k][dr];
      *(uint4*)&Vt[((size_t)((b * NH + h) * HD + d0 + dr)) * SEQ + s0 + ch * 8] = *(const uint4*)tmp;
    }
  }
}

// ---------- 7. flash attention: double-buffered K, late-issued V, counted vmcnt ----------
#define PSTR 68

__global__ __launch_bounds__(256, 2) void k_flash(const unsigned short* __restrict__ Qb,
                                               const unsigned short* __restrict__ Kb,
                                               const unsigned short* __restrict__ Vt,
                                               const unsigned short* __restrict__ AKb,
                                               const unsigned short* __restrict__ avt,
                                               const float* __restrict__ gate,
                                               unsigned short* __restrict__ Obuf,
                                               float* __restrict__ ml,
                                               unsigned short* __restrict__ Aout) {
  const int L = blockIdx.x;            // 0..639, h in low bits
  const int h = L & 15;
  const int slot = 39 - (L >> 4);      // heavy-first dispatch
  const int b = blockIdx.y;
  int qt, j, P;
  if (slot < 4)       { qt = slot;               j = 0;          P = 1; }
  else if (slot < 12) { int s = slot - 4;  qt = 4 + (s >> 1);  j = s & 1; P = 2; }
  else if (slot < 24) { int s = slot - 12; qt = 8 + s / 3;     j = s % 3; P = 3; }
  else                { int s = slot - 24; qt = 12 + (s >> 2); j = s & 3; P = 4; }

  const int t = threadIdx.x, w = t >> 6, lane = t & 63;
  const int lr = lane & 15, quad = lane >> 4;

  __shared__ unsigned short Ks[2 * 64 * 128];   // double-buffered, swizzled 16B chunks
  __shared__ unsigned short Vs[128 * 64];
  __shared__ unsigned short Ps[4][32 * PSTR];
  unsigned short* Ps16 = &Ps[w][0];

  const int row_base = qt * 128 + w * 32;

  bf16x8 qf[2][4];
  #pragma unroll
  for (int mt = 0; mt < 2; mt++)
    #pragma unroll
    for (int kk = 0; kk < 4; kk++)
      qf[mt][kk] = *(const bf16x8*)&Qb[((size_t)(b * SEQ + row_base + mt * 16 + lr)) * DMODEL
                                       + h * HD + kk * 32 + quad * 8];

  f32x4 o[2][8];
  #pragma unroll
  for (int mt = 0; mt < 2; mt++)
    #pragma unroll
    for (int nt = 0; nt < 8; nt++) o[mt][nt] = (f32x4){0.f, 0.f, 0.f, 0.f};
  float l_i[2][4];
  #pragma unroll
  for (int mt = 0; mt < 2; mt++)
    #pragma unroll
    for (int r = 0; r < 4; r++) l_i[mt][r] = 0.f;

  const int krow = t >> 4;
  const int vd = t >> 3, vc = (t & 7) ^ (vd & 7);
  const int ktend = 2 * qt + 2;

  #pragma unroll
  for (int jj = 0; jj < 4; jj++) {
    int row = krow + jj * 16;
    int c = (t & 15) ^ (row & 15);
    GLOAD_LDS16(&Kb[((size_t)(b * SEQ + j * 64 + row)) * DMODEL + h * HD + c * 8],
                &Ks[(t + jj * 256) * 8]);
  }
  #pragma unroll
  for (int jj = 0; jj < 4; jj++) {
    int d = vd + jj * 32;
    GLOAD_LDS16(&Vt[((size_t)((b * NH + h) * HD + d)) * SEQ + j * 64 + vc * 8],
                &Vs[(t + jj * 256) * 8]);
  }

  int kb = 0;
  for (int kt = j; kt < ktend; kt += P) {
    const bool more = (kt + P < ktend);
    const int kbase = kb * 8192;
    const int nkbase = 8192 - kbase;

    WAITVM(4);
    SBAR();

    f32x4 s4[2][4];
    #pragma unroll
    for (int mt = 0; mt < 2; mt++)
      #pragma unroll
      for (int nt = 0; nt < 4; nt++) s4[mt][nt] = (f32x4){0.f, 0.f, 0.f, 0.f};
    #pragma unroll
    for (int nt = 0; nt < 4; nt++)
      #pragma unroll
      for (int kk = 0; kk < 4; kk++) {
        bf16x8 bv = *(const bf16x8*)&Ks[kbase + ((nt * 16 + lr) * 16 + ((kk * 4 + quad) ^ lr)) * 8];
        s4[0][nt] = __builtin_amdgcn_mfma_f32_16x16x32_bf16(qf[0][kk], bv, s4[0][nt], 0, 0, 0);
        s4[1][nt] = __builtin_amdgcn_mfma_f32_16x16x32_bf16(qf[1][kk], bv, s4[1][nt], 0, 0, 0);
      }

    if (more) {
      #pragma unroll
      for (int jj = 0; jj < 4; jj++) {
        int row = krow + jj * 16;
        int c = (t & 15) ^ (row & 15);
        GLOAD_LDS16(&Kb[((size_t)(b * SEQ + (kt + P) * 64 + row)) * DMODEL + h * HD + c * 8],
                    &Ks[nkbase + (t + jj * 256) * 8]);
      }
    }

    const int maybe_mask = (kt * 64 + 63 > row_base);
    #pragma unroll
    for (int mt = 0; mt < 2; mt++) {
      #pragma unroll
      for (int nt = 0; nt < 4; nt++) s4[mt][nt] = s4[mt][nt] * SCALEL2;
      if (maybe_mask) {
        #pragma unroll
        for (int nt = 0; nt < 4; nt++) {
          int col = kt * 64 + nt * 16 + lr;
          #pragma unroll
          for (int r = 0; r < 4; r++)
            if (col > row_base + mt * 16 + quad * 4 + r) s4[mt][nt][r] = -__builtin_inff();
        }
      }
      #pragma unroll
      for (int nt = 0; nt < 4; nt++)
        #pragma unroll
        for (int r = 0; r < 4; r++) {
          float p = __builtin_amdgcn_exp2f(s4[mt][nt][r]);
          l_i[mt][r] += p;
          Ps[w][(mt * 16 + quad * 4 + r) * PSTR + nt * 16 + lr] = f2bf(p);
        }
    }

    if (more) WAITVM(4); else WAITVM(0);
    SBAR();

    #pragma unroll
    for (int kk2 = 0; kk2 < 2; kk2++) {
      bf16x8 af0 = *(const bf16x8*)&Ps[w][(lr) * PSTR + kk2 * 32 + quad * 8];
      bf16x8 af1 = *(const bf16x8*)&Ps[w][(16 + lr) * PSTR + kk2 * 32 + quad * 8];
      #pragma unroll
      for (int nt = 0; nt < 8; nt++) {
        bf16x8 bv = *(const bf16x8*)&Vs[((nt * 16 + lr) * 8 + ((kk2 * 4 + quad) ^ (lr & 7))) * 8];
        o[0][nt] = __builtin_amdgcn_mfma_f32_16x16x32_bf16(af0, bv, o[0][nt], 0, 0, 0);
        o[1][nt] = __builtin_amdgcn_mfma_f32_16x16x32_bf16(af1, bv, o[1][nt], 0, 0, 0);
      }
    }

    SBAR();
    if (more) {
      #pragma unroll
      for (int jj = 0; jj < 4; jj++) {
        int d = vd + jj * 32;
        GLOAD_LDS16(&Vt[((size_t)((b * NH + h) * HD + d)) * SEQ + (kt + P) * 64 + vc * 8],
                    &Vs[(t + jj * 256) * 8]);
      }
    }
    kb ^= 1;
  }

  #pragma unroll
  for (int mt = 0; mt < 2; mt++)
    #pragma unroll
    for (int r = 0; r < 4; r++) {
      float l = l_i[mt][r];
      #pragma unroll
      for (int off = 1; off < 16; off <<= 1) l += __shfl_xor(l, off, 64);
      l_i[mt][r] = l;
    }

  const size_t slotg = (size_t)(b * 16 + h) * 40 + slot;

  if (j == 0) {
    const float g = gate[h];
    #pragma unroll
    for (int mt = 0; mt < 2; mt++) {
      f32x4 as4 = (f32x4){0.f, 0.f, 0.f, 0.f};
      #pragma unroll
      for (int kk = 0; kk < 4; kk++) {
        bf16x8 akf = *(const bf16x8*)&AKb[(size_t)lr * DMODEL + h * HD + kk * 32 + quad * 8];
        as4 = __builtin_amdgcn_mfma_f32_16x16x32_bf16(qf[mt][kk], akf, as4, 0, 0, 0);
      }
      as4 = as4 * SCALEL2;
      float al[4];
      #pragma unroll
      for (int r = 0; r < 4; r++) {
        float p = (lr < NP) ? __builtin_amdgcn_exp2f(as4[r]) : 0.f;
        as4[r] = p;
        float sum = p;
        #pragma unroll
        for (int off = 1; off < 16; off <<= 1) sum += __shfl_xor(sum, off, 64);
        al[r] = sum;
      }
      #pragma unroll
      for (int r = 0; r < 4; r++) {
        Ps[w][(mt * 16 + quad * 4 + r) * PSTR + lr] = f2bf(as4[r]);
        Ps[w][(mt * 16 + quad * 4 + r) * PSTR + 16 + lr] = 0;
      }
      bf16x8 af = *(const bf16x8*)&Ps[w][(mt * 16 + lr) * PSTR + quad * 8];
      f32x4 pa[8];
      #pragma unroll
      for (int nt = 0; nt < 8; nt++) {
        bf16x8 bv = *(const bf16x8*)&avt[(size_t)(h * HD + nt * 16 + lr) * 32 + quad * 8];
        pa[nt] = __builtin_amdgcn_mfma_f32_16x16x32_bf16(af, bv, (f32x4){0.f, 0.f, 0.f, 0.f}, 0, 0, 0);
      }
      float invla[4];
      #pragma unroll
      for (int r = 0; r < 4; r++) invla[r] = g / al[r];
      #pragma unroll
      for (int nt = 0; nt < 8; nt++)
        #pragma unroll
        for (int r = 0; r < 4; r++)
          Ps16[(quad * 4 + r) * 128 + nt * 16 + lr] = f2bf(pa[nt][r] * invla[r]);
      size_t gb = (((size_t)(b * 16 + h) * 16 + qt)) * 16384 + (size_t)(w * 32 + mt * 16) * 128;
      #pragma unroll
      for (int it = 0; it < 4; it++) {
        int i = lane + it * 64;
        int rr = i >> 4, ch = i & 15;
        *(uint4*)&Aout[gb + rr * 128 + ch * 8] = *(const uint4*)&Ps16[rr * 128 + ch * 8];
      }
    }
  }

  #pragma unroll
  for (int mt = 0; mt < 2; mt++) {
    if (lr == 0) {
      #pragma unroll
      for (int r = 0; r < 4; r++) {
        int rl = w * 32 + mt * 16 + quad * 4 + r;
        ml[slotg * 128 + rl] = l_i[mt][r];
      }
    }
    #pragma unroll
    for (int nt = 0; nt < 8; nt++)
      #pragma unroll
      for (int r = 0; r < 4; r++)
        Ps16[(quad * 4 + r) * 128 + nt * 16 + lr] = f2bf(o[mt][nt][r]);
    size_t gb = slotg * 16384 + (size_t)(w * 32 + mt * 16) * 128;
    #pragma unroll
    for (int it = 0; it < 4; it++) {
      int i = lane + it * 64;
      int rr = i >> 4, ch = i & 15;
      *(uint4*)&Obuf[gb + rr * 128 + ch * 8] = *(const uint4*)&Ps16[rr * 128 + ch * 8];
    }
  }
}

// ---------- 8. merge split partials + adapter ----------
__global__ __launch_bounds__(256) void k_merge(const unsigned short* __restrict__ Obuf,
                                               const float* __restrict__ ml,
                                               const unsigned short* __restrict__ Aout,
                                               unsigned short* __restrict__ ab) {
  int idx = blockIdx.x * 256 + threadIdx.x;     // 2^20
  int ch = idx & 15;
  int row = (idx >> 4) & 2047;
  int h = (idx >> 15) & 15;
  int b = idx >> 19;
  int qt = row >> 7, rl = row & 127;
  int start = qt < 4 ? qt : qt < 8 ? 4 + 2 * (qt - 4) : qt < 12 ? 12 + 3 * (qt - 8) : 24 + 4 * (qt - 12);
  int P = qt < 4 ? 1 : qt < 8 ? 2 : qt < 12 ? 3 : 4;
  size_t sbase = (size_t)(b * 16 + h) * 40 + start;
  float den = 0.f;
  float acc[8] = {0.f, 0.f, 0.f, 0.f, 0.f, 0.f, 0.f, 0.f};
  #pragma unroll
  for (int jp = 0; jp < 4; jp++) {
    if (jp < P) {
      den += ml[(sbase + jp) * 128 + rl];
      uint4 ov = *(const uint4*)&Obuf[(sbase + jp) * 16384 + rl * 128 + ch * 8];
      const unsigned short* pv = (const unsigned short*)&ov;
      #pragma unroll
      for (int k = 0; k < 8; k++) acc[k] += bf2f(pv[k]);
    }
  }
  uint4 av = *(const uint4*)&Aout[(((size_t)(b * 16 + h) * 16 + qt)) * 16384 + rl * 128 + ch * 8];
  const unsigned short* pa = (const unsigned short*)&av;
  float dn = 1.0f / den;
  unsigned short res[8];
  #pragma unroll
  for (int k = 0; k < 8; k++) res[k] = f2bf(acc[k] * dn + bf2f(pa[k]));
  *(uint4*)&ab[((size_t)(b * 2048 + row)) * 2048 + h * 128 + ch * 8] = *(const uint4*)res;
}

// ---------- launcher ----------
extern "C" void kernel_launch(void* const* d_in, const int* in_sizes, int n_in,
                              void* d_out, int out_size, void* d_ws, size_t ws_size,
                              hipStream_t stream) {
  const float* hidden = (const float*)d_in[0];
  const float* Wq = (const float*)d_in[3];
  const float* Wk = (const float*)d_in[4];
  const float* Wv = (const float*)d_in[5];
  const float* Wo = (const float*)d_in[6];
  const float* Aq = (const float*)d_in[7];
  const float* gate = (const float*)d_in[8];
  float* out = (float*)d_out;

  char* ws = (char*)d_ws;
  size_t off = 0;
  auto alloc = [&](size_t bytes) -> void* {
    void* p = ws + off;
    off = (off + bytes + 255) & ~(size_t)255;
    return p;
  };
  unsigned short* wt   = (unsigned short*)alloc((size_t)4 * DMODEL * DMODEL * 2);
  unsigned short* xaug = (unsigned short*)alloc((size_t)MAUG * DMODEL * 2);
  unsigned short* qkvb = (unsigned short*)alloc((size_t)3 * MAUG * DMODEL * 2);
  unsigned short* qf = qkvb;
  unsigned short* kf = qkvb + (size_t)MAUG * DMODEL;
  unsigned short* vf = kf + (size_t)MAUG * DMODEL;
  unsigned short* qb  = (unsigned short*)alloc((size_t)NB * SEQ * DMODEL * 2);
  unsigned short* kb  = (unsigned short*)alloc((size_t)NB * SEQ * DMODEL * 2);
  unsigned short* vt  = (unsigned short*)alloc((size_t)NB * SEQ * DMODEL * 2);
  unsigned short* akb = (unsigned short*)alloc((size_t)16 * DMODEL * 2);
  unsigned short* avt = (unsigned short*)alloc((size_t)DMODEL * 32 * 2);
  float* cost = (float*)alloc((size_t)SEQ * HD * 4);
  float* sint = (float*)alloc((size_t)SEQ * HD * 4);
  unsigned short* obuf = (unsigned short*)alloc((size_t)NB * NH * 40 * 16384 * 2);
  float* mlb = (float*)alloc((size_t)NB * NH * 40 * 128 * 4);
  unsigned short* aout = (unsigned short*)alloc((size_t)NB * NH * 16 * 16384 * 2);
  unsigned short* ab = qf;   // reuse: qf dead after k_ropevt

  k_prep<<<512 + 4096 + 4106, 256, 0, stream>>>(Wq, Wk, Wv, Wo, hidden, Aq, wt, xaug, cost, sint);
  k_gemm256<1><<<dim3(408), 512, 0, stream>>>(xaug, wt, qkvb, MAUG, (size_t)MAUG * DMODEL);
  k_ropevt<<<MAUG + 2048, 256, 0, stream>>>(qf, kf, vf, cost, sint, qb, kb, akb, avt, vt);
  k_flash<<<dim3(640, 2), 256, 0, stream>>>(qb, kb, vt, akb, avt, gate, obuf, mlb, aout);
  k_merge<<<4096, 256, 0, stream>>>(obuf, mlb, aout, ab);
  k_gemmo<<<dim3(256), 512, 0, stream>>>(ab, wt + (size_t)3 * DMODEL * DMODEL, out);
}

// Round 10
// 398.939 us; speedup vs baseline: 1.0295x; 1.0295x over previous
//
#include <hip/hip_runtime.h>
#include <cstdint>
#include <cstddef>
#include <cmath>

typedef __bf16 bf16x8 __attribute__((ext_vector_type(8)));
typedef float  f32x4  __attribute__((ext_vector_type(4)));

__device__ __forceinline__ unsigned short f2bf(float f) {
  unsigned int u = __float_as_uint(f);
  u += 0x7FFF + ((u >> 16) & 1);
  return (unsigned short)(u >> 16);
}
__device__ __forceinline__ float bf2f(unsigned short u) {
  return __uint_as_float(((unsigned int)u) << 16);
}

#define SEQ 2048
#define DMODEL 2048
#define NH 16
#define HD 128
#define NB 2
#define NP 10
#define MAUG 4106
#define SCALEL2 (0.08838834764831845f * 1.44269504088896340f)

#define GLOAD_LDS16(g, l) \
  __builtin_amdgcn_global_load_lds((__attribute__((address_space(1))) const void*)(g), \
                                   (__attribute__((address_space(3))) void*)(l), 16, 0, 0)

#define FENCE() asm volatile("" ::: "memory")
#define SBAR() do { FENCE(); __builtin_amdgcn_s_barrier(); FENCE(); } while (0)
#define WAITVM(N) asm volatile("s_waitcnt vmcnt(" #N ")" ::: "memory")

// ---------- 1+2+3 fused preprocessing: tables | weight transpose | x-aug ----------
__global__ __launch_bounds__(256) void k_prep(const float* __restrict__ W0,
                                              const float* __restrict__ W1,
                                              const float* __restrict__ W2,
                                              const float* __restrict__ W3,
                                              const float* __restrict__ X,
                                              const float* __restrict__ Aq,
                                              unsigned short* __restrict__ wt,
                                              unsigned short* __restrict__ xaug,
                                              float* __restrict__ cost,
                                              float* __restrict__ sint) {
  __shared__ float tile[64][65];   // pad 65: transposed reads 2-way (free)
  const int bid = blockIdx.x;
  const int t = threadIdx.x;
  if (bid < 512) {
    // ---- RoPE tables (f32; reference computes in f32, tol 1.5e-2) ----
    int idx = bid * 256 + t;
    int s = idx >> 6, i = idx & 63;
    float invf = expf(-((float)(2 * i) / 128.0f) * logf(10000.0f));
    float a = (float)s * invf;
    float c = cosf(a), sn = sinf(a);
    cost[s * HD + i] = c;  cost[s * HD + 64 + i] = c;
    sint[s * HD + i] = sn; sint[s * HD + 64 + i] = sn;
  } else if (bid < 512 + 4096) {
    // ---- weight transpose + cast: 64x64 tiles ----
    int wi = bid - 512;
    int zw = wi >> 10, rem = wi & 1023;
    const float* W = (zw == 0) ? W0 : (zw == 1) ? W1 : (zw == 2) ? W2 : W3;
    unsigned short* o = wt + (size_t)zw * DMODEL * DMODEL;
    int c = t & 15, r0 = t >> 4;
    int bx = (rem & 31) * 64, by = (rem >> 5) * 64;
    #pragma unroll
    for (int jj = 0; jj < 4; jj++) {
      int r = r0 + jj * 16;
      float4 v = *(const float4*)&W[(size_t)(bx + r) * DMODEL + by + c * 4];
      tile[r][c * 4 + 0] = v.x; tile[r][c * 4 + 1] = v.y;
      tile[r][c * 4 + 2] = v.z; tile[r][c * 4 + 3] = v.w;
    }
    __syncthreads();
    #pragma unroll
    for (int jj = 0; jj < 4; jj++) {
      int ro = r0 + jj * 16;
      unsigned short s4[4];
      #pragma unroll
      for (int k = 0; k < 4; k++) s4[k] = f2bf(tile[c * 4 + k][ro]);
      *(uint2*)&o[(size_t)(by + ro) * DMODEL + bx + c * 4] = *(const uint2*)s4;
    }
  } else {
    // ---- X augmented + cast: 8 elems/thread ----
    int xi = bid - 4608;
    size_t u = ((size_t)xi * 256 + t) * 8;
    size_t row = u >> 11;
    int col = (int)(u & 2047);
    const float* src = (row < (size_t)NB * SEQ) ? &X[u]
                                                : &Aq[(row - NB * SEQ) * DMODEL + col];
    float4 a = *(const float4*)src;
    float4 b = *(const float4*)(src + 4);
    unsigned short r[8] = { f2bf(a.x), f2bf(a.y), f2bf(a.z), f2bf(a.w),
                            f2bf(b.x), f2bf(b.y), f2bf(b.z), f2bf(b.w) };
    *(uint4*)&xaug[u] = *(const uint4*)r;
  }
}

// ---------- 4a. QKV GEMM: 256x256, BK=64, read-ahead 4-phase + FUSED epilogue ----------
// Epilogue per z: z=0/1 -> RoPE via LDS-staged tile (pair d^64 crosses waves);
// z=1 adapter tile -> AKb; z=2 -> in-LDS transpose -> Vt; z=2 adapter -> avt (+zero pad).
// Numerics bit-identical to the old qkvb->ropevt path (bf16 staged both ways).
#define RD_A(dst, bb, MH) do { \
  _Pragma("unroll") for (int i_ = 0; i_ < 4; i_++) \
    _Pragma("unroll") for (int ks_ = 0; ks_ < 2; ks_++) \
      dst[i_][ks_] = *(const bf16x8*)&lds[(bb) + (wr*128 + (MH)*64 + i_*16 + lr)*64 + (((ks_*4+quad) ^ (lr & 7)) * 8)]; \
} while (0)

#define RD_B(dst, bb, NHH) do { \
  _Pragma("unroll") for (int j_ = 0; j_ < 2; j_++) \
    _Pragma("unroll") for (int ks_ = 0; ks_ < 2; ks_++) \
      dst[j_][ks_] = *(const bf16x8*)&lds[(bb) + 16384 + (wc*64 + (NHH)*32 + j_*16 + lr)*64 + (((ks_*4+quad) ^ (lr & 7)) * 8)]; \
} while (0)

#define MM(A, B, MH, NHH) do { \
  __builtin_amdgcn_s_setprio(1); \
  _Pragma("unroll") for (int i_ = 0; i_ < 4; i_++) \
    _Pragma("unroll") for (int j_ = 0; j_ < 2; j_++) { \
      acc[(MH)*4+i_][(NHH)*2+j_] = __builtin_amdgcn_mfma_f32_16x16x32_bf16(A[i_][0], B[j_][0], acc[(MH)*4+i_][(NHH)*2+j_], 0, 0, 0); \
      acc[(MH)*4+i_][(NHH)*2+j_] = __builtin_amdgcn_mfma_f32_16x16x32_bf16(A[i_][1], B[j_][1], acc[(MH)*4+i_][(NHH)*2+j_], 0, 0, 0); \
    } \
  __builtin_amdgcn_s_setprio(0); \
} while (0)

#define STG_AE(nb, ko) do { \
  GLOAD_LDS16(sA + (ko),                      &lds[(nb)*32768 + (qrow)*64 + g8]); \
  GLOAD_LDS16(sA + 128*(size_t)DMODEL + (ko), &lds[(nb)*32768 + (128+qrow)*64 + g8]); } while (0)
#define STG_AO(nb, ko) do { \
  GLOAD_LDS16(sA + 64*(size_t)DMODEL + (ko),  &lds[(nb)*32768 + (64+qrow)*64 + g8]); \
  GLOAD_LDS16(sA + 192*(size_t)DMODEL + (ko), &lds[(nb)*32768 + (192+qrow)*64 + g8]); } while (0)
#define STG_BE(nb, ko) do { \
  GLOAD_LDS16(sB + (ko),                      &lds[(nb)*32768 + 16384 + (qbr)*64 + g8]); \
  GLOAD_LDS16(sB + 128*(size_t)DMODEL + (ko), &lds[(nb)*32768 + 16384 + (128+qbr)*64 + g8]); } while (0)
#define STG_BO(nb, ko) do { \
  GLOAD_LDS16(sB + 32*(size_t)DMODEL + (ko),  &lds[(nb)*32768 + 16384 + (32+qbr)*64 + g8]); \
  GLOAD_LDS16(sB + 160*(size_t)DMODEL + (ko), &lds[(nb)*32768 + 16384 + (160+qbr)*64 + g8]); } while (0)

__global__ __launch_bounds__(512, 2) void k_gemmqkv(const unsigned short* __restrict__ A,
                                                    const unsigned short* __restrict__ Bt,
                                                    const float* __restrict__ cost,
                                                    const float* __restrict__ sint,
                                                    unsigned short* __restrict__ Qb,
                                                    unsigned short* __restrict__ Kb,
                                                    unsigned short* __restrict__ Vt,
                                                    unsigned short* __restrict__ AKb,
                                                    unsigned short* __restrict__ avt) {
  __shared__ unsigned short lds[65536];   // 128 KiB: [2 bufs][A 256x64 | B 256x64]; epilogue: 256x256 tile
  const int t = threadIdx.x;
  const int lane = t & 63, w = t >> 6;
  const int lr = lane & 15, quad = lane >> 4;
  const int wr = w >> 2, wc = w & 3;       // 2x4 wave grid; per-wave 128x64 output
  // XCD-aware bijective swizzle (gridDim.x % 8 == 0)
  const int tm = (MAUG + 255) >> 8;        // 17
  const int perz = tm * 8;                 // 136
  const int qchunk = gridDim.x >> 3;
  const int lin = ((int)blockIdx.x & 7) * qchunk + ((int)blockIdx.x >> 3);
  const int z = lin / perz;
  const int rem = lin - z * perz;
  const int m0 = (rem >> 3) * 256, n0 = (rem & 7) * 256;
  const unsigned short* Bz = Bt + (size_t)z * DMODEL * DMODEL;

  const int qrow = t >> 3;
  const int g8 = (t & 7) * 8;
  const int gsw8 = (((t & 7) ^ (qrow & 7)) * 8);        // pre-swizzled source granule
  const int qbr = (qrow < 32) ? qrow : qrow + 32;       // B-block row pattern

  const unsigned short* sA = A + (size_t)(m0 + qrow) * DMODEL + gsw8;
  const unsigned short* sB = Bz + (size_t)(n0 + qbr) * DMODEL + gsw8;

  bf16x8 aE[4][2], aO[4][2], bE[2][2], bO[2][2];
  f32x4 acc[8][4];
  #pragma unroll
  for (int i = 0; i < 8; i++)
    #pragma unroll
    for (int j = 0; j < 4; j++) acc[i][j] = (f32x4){0.f, 0.f, 0.f, 0.f};

  STG_AE(0, 0); STG_BE(0, 0); STG_BO(0, 0); STG_AO(0, 0);
  WAITVM(4);
  SBAR();
  RD_A(aE, 0, 0); RD_B(bE, 0, 0);

  for (int kt = 0; kt < DMODEL / 64; kt++) {
    const int base = (kt & 1) << 15;
    const int nb2 = (kt & 1) ^ 1;
    const int nbase = nb2 << 15;
    const int ko = (kt + 1) * 64;
    const bool more = (kt + 1 < DMODEL / 64);

    if (more) { STG_AE(nb2, ko); WAITVM(4); } else WAITVM(2);
    SBAR();
    RD_B(bO, base, 1);
    MM(aE, bE, 0, 0);

    if (more) { STG_BE(nb2, ko); WAITVM(4); } else WAITVM(0);
    SBAR();
    RD_A(aO, base, 1);
    MM(aE, bO, 0, 1);

    if (more) STG_BO(nb2, ko);
    MM(aO, bE, 1, 0);

    if (more) {
      STG_AO(nb2, ko);
      WAITVM(4);
      SBAR();
      RD_A(aE, nbase, 0); RD_B(bE, nbase, 0);
    }
    MM(aO, bO, 1, 1);
  }

  // ---------------- fused epilogue ----------------
  const int rl0 = wr * 128;
  const int cl0 = wc * 64;

  if (z <= 1) {
    if (m0 < NB * SEQ) {
      // RoPE: stage bf16 tile in LDS (swizzled: cl ^ ((rl>>2)&7)<<3 to spread banks)
      unsigned short* dst = (z == 0) ? Qb : Kb;
      SBAR();
      #pragma unroll
      for (int mi = 0; mi < 8; mi++)
        #pragma unroll
        for (int r = 0; r < 4; r++) {
          int rl = rl0 + mi * 16 + quad * 4 + r;
          int P = ((rl >> 2) & 7) << 3;
          #pragma unroll
          for (int n = 0; n < 4; n++) {
            int cl = cl0 + n * 16 + lr;
            lds[rl * 256 + (cl ^ P)] = f2bf(acc[mi][n][r]);
          }
        }
      SBAR();
      #pragma unroll
      for (int mi = 0; mi < 8; mi++)
        #pragma unroll
        for (int r = 0; r < 4; r++) {
          int rl = rl0 + mi * 16 + quad * 4 + r;
          int P = ((rl >> 2) & 7) << 3;
          int srow = m0 + rl;
          int s = srow & (SEQ - 1);
          #pragma unroll
          for (int n = 0; n < 4; n++) {
            int cl = cl0 + n * 16 + lr;
            int d = cl & 127;
            float v  = bf2f(lds[rl * 256 + (cl ^ P)]);
            float vp = bf2f(lds[rl * 256 + ((cl ^ 64) ^ P)]);
            float cv = cost[s * HD + d], sv = sint[s * HD + d];
            float o = v * cv + ((d < 64) ? -vp : vp) * sv;
            dst[(size_t)srow * DMODEL + n0 + cl] = f2bf(o);
          }
        }
    } else if (z == 1) {
      // adapter K rows (no RoPE): p = rl since m0 == 4096
      #pragma unroll
      for (int mi = 0; mi < 8; mi++)
        #pragma unroll
        for (int r = 0; r < 4; r++) {
          int p = rl0 + mi * 16 + quad * 4 + r;
          if (p < NP) {
            #pragma unroll
            for (int n = 0; n < 4; n++)
              AKb[(size_t)p * DMODEL + n0 + cl0 + n * 16 + lr] = f2bf(acc[mi][n][r]);
          }
        }
    }
  } else {
    if (m0 < NB * SEQ) {
      // V transpose: swizzled LDS [cl][rl], then coalesced Vt stores
      SBAR();
      #pragma unroll
      for (int mi = 0; mi < 8; mi++)
        #pragma unroll
        for (int r = 0; r < 4; r++) {
          int rl = rl0 + mi * 16 + quad * 4 + r;
          #pragma unroll
          for (int n = 0; n < 4; n++) {
            int cl = cl0 + n * 16 + lr;
            lds[cl * 256 + (rl ^ ((cl & 7) << 3))] = f2bf(acc[mi][n][r]);
          }
        }
      SBAR();
      const int bidx = m0 >> 11;
      const int scol = m0 & 2047;
      #pragma unroll
      for (int rep = 0; rep < 4; rep++) {
        int dr = (t >> 3) + rep * 64;
        int hh = (n0 + dr) >> 7, dd = (n0 + dr) & 127;
        size_t vbase = ((size_t)((bidx * NH + hh) * HD + dd)) * SEQ + scol;
        #pragma unroll
        for (int i = 0; i < 4; i++) {
          int s0 = (t & 7) * 8 + i * 64;
          int lbase = dr * 256 + (s0 ^ ((dr & 7) << 3));   // 8 shorts contiguous
          *(uint4*)&Vt[vbase + s0] = *(const uint4*)&lds[lbase];
        }
      }
    } else {
      // adapter V rows -> avt[col][p], zero-fill p in [NP,32)
      #pragma unroll
      for (int mi = 0; mi < 8; mi++)
        #pragma unroll
        for (int r = 0; r < 4; r++) {
          int p = rl0 + mi * 16 + quad * 4 + r;
          if (p < 32) {
            #pragma unroll
            for (int n = 0; n < 4; n++) {
              int cl = cl0 + n * 16 + lr;
              avt[(size_t)(n0 + cl) * 32 + p] = (p < NP) ? f2bf(acc[mi][n][r]) : (unsigned short)0;
            }
          }
        }
    }
  }
}

// ---------- 4b. out-proj GEMM: 128x256 tile, grid 256 blocks, XCD-swizzled ----------
#define O_LDA(MH) do { \
  _Pragma("unroll") for (int i_ = 0; i_ < 2; i_++) \
    _Pragma("unroll") for (int ks_ = 0; ks_ < 2; ks_++) \
      a[i_][ks_] = *(const bf16x8*)&lds[base + (wr*64 + ((MH)*2+i_)*16 + lr)*64 + (((ks_*4+quad) ^ (lr & 7)) * 8)]; \
} while (0)

#define O_LDB(NHH) do { \
  _Pragma("unroll") for (int j_ = 0; j_ < 2; j_++) \
    _Pragma("unroll") for (int ks_ = 0; ks_ < 2; ks_++) \
      b[(NHH)*2+j_][ks_] = *(const bf16x8*)&lds[base + 8192 + (wc*64 + ((NHH)*2+j_)*16 + lr)*64 + (((ks_*4+quad) ^ (lr & 7)) * 8)]; \
} while (0)

#define O_MFMA(MH, NHH) do { \
  __builtin_amdgcn_s_setprio(1); \
  _Pragma("unroll") for (int i_ = 0; i_ < 2; i_++) \
    _Pragma("unroll") for (int j_ = 0; j_ < 2; j_++) { \
      acc[(MH)*2+i_][(NHH)*2+j_] = __builtin_amdgcn_mfma_f32_16x16x32_bf16(a[i_][0], b[(NHH)*2+j_][0], acc[(MH)*2+i_][(NHH)*2+j_], 0, 0, 0); \
      acc[(MH)*2+i_][(NHH)*2+j_] = __builtin_amdgcn_mfma_f32_16x16x32_bf16(a[i_][1], b[(NHH)*2+j_][1], acc[(MH)*2+i_][(NHH)*2+j_], 0, 0, 0); \
    } \
  __builtin_amdgcn_s_setprio(0); \
} while (0)

#define O_STG_AE(nb, ko) GLOAD_LDS16(sA + (ko), &lds[(nb)*24576 + (qb)*64 + g8])
#define O_STG_AO(nb, ko) GLOAD_LDS16(sA + 32*(size_t)DMODEL + (ko), &lds[(nb)*24576 + (32+qb)*64 + g8])
#define O_STG_BE(nb, ko) do { \
  GLOAD_LDS16(sB + (ko),                      &lds[(nb)*24576 + 8192 + (qb)*64 + g8]); \
  GLOAD_LDS16(sB + 128*(size_t)DMODEL + (ko), &lds[(nb)*24576 + 8192 + (128+qb)*64 + g8]); } while (0)
#define O_STG_BO(nb, ko) do { \
  GLOAD_LDS16(sB + 32*(size_t)DMODEL + (ko),  &lds[(nb)*24576 + 8192 + (32+qb)*64 + g8]); \
  GLOAD_LDS16(sB + 160*(size_t)DMODEL + (ko), &lds[(nb)*24576 + 8192 + (160+qb)*64 + g8]); } while (0)

__global__ __launch_bounds__(512, 2) void k_gemmo(const unsigned short* __restrict__ A,
                                                  const unsigned short* __restrict__ Bt,
                                                  float* __restrict__ C) {
  __shared__ unsigned short lds[49152];   // 96 KiB: [2 bufs][A 128x64 | B 256x64]
  const int t = threadIdx.x;
  const int lane = t & 63, w = t >> 6;
  const int lr = lane & 15, quad = lane >> 4;
  const int wr = w >> 2, wc = w & 3;
  const int lin = ((int)blockIdx.x & 7) * 32 + ((int)blockIdx.x >> 3);
  const int m0 = (lin >> 3) * 128, n0 = (lin & 7) * 256;

  const int qrow = t >> 3;
  const int g8 = (t & 7) * 8;
  const int gsw8 = (((t & 7) ^ (qrow & 7)) * 8);
  const int qb = (qrow < 32) ? qrow : qrow + 32;

  const unsigned short* sA = A + (size_t)(m0 + qb) * DMODEL + gsw8;
  const unsigned short* sB = Bt + (size_t)(n0 + qb) * DMODEL + gsw8;

  bf16x8 a[2][2], b[4][2];
  f32x4 acc[4][4];
  #pragma unroll
  for (int i = 0; i < 4; i++)
    #pragma unroll
    for (int j = 0; j < 4; j++) acc[i][j] = (f32x4){0.f, 0.f, 0.f, 0.f};

  O_STG_AE(0, 0); O_STG_BE(0, 0); O_STG_BO(0, 0); O_STG_AO(0, 0);
  WAITVM(3);
  SBAR();

  for (int kt = 0; kt < DMODEL / 64; kt++) {
    const int base = (kt & 1) * 24576;
    const int nb = (kt & 1) ^ 1;
    const int ko = (kt + 1) * 64;
    const bool more = (kt + 1 < DMODEL / 64);

    O_LDA(0);
    O_LDB(0);
    if (more) O_STG_AE(nb, ko);
    SBAR();
    O_MFMA(0, 0);
    if (more) WAITVM(2); else WAITVM(1);
    SBAR();

    O_LDB(1);
    if (more) O_STG_BE(nb, ko);
    SBAR();
    O_MFMA(0, 1);
    if (more) WAITVM(3); else WAITVM(0);
    SBAR();

    O_LDA(1);
    if (more) O_STG_BO(nb, ko);
    SBAR();
    O_MFMA(1, 0);
    SBAR();

    if (more) O_STG_AO(nb, ko);
    SBAR();
    O_MFMA(1, 1);
    if (more) WAITVM(3);
    SBAR();
  }

  #pragma unroll
  for (int mi = 0; mi < 4; mi++) {
    #pragma unroll
    for (int r = 0; r < 4; r++) {
      int row = m0 + wr * 64 + mi * 16 + quad * 4 + r;
      #pragma unroll
      for (int n = 0; n < 4; n++)
        C[(size_t)row * DMODEL + n0 + wc * 64 + n * 16 + lr] = acc[mi][n][r];
    }
  }
}

// ---------- 7. flash attention: double-buffered K, late-issued V, counted vmcnt ----------
#define PSTR 68

__global__ __launch_bounds__(256, 2) void k_flash(const unsigned short* __restrict__ Qb,
                                               const unsigned short* __restrict__ Kb,
                                               const unsigned short* __restrict__ Vt,
                                               const unsigned short* __restrict__ AKb,
                                               const unsigned short* __restrict__ avt,
                                               const float* __restrict__ gate,
                                               unsigned short* __restrict__ Obuf,
                                               float* __restrict__ ml,
                                               unsigned short* __restrict__ Aout) {
  const int L = blockIdx.x;            // 0..639, h in low bits
  const int h = L & 15;
  const int slot = 39 - (L >> 4);      // heavy-first dispatch
  const int b = blockIdx.y;
  int qt, j, P;
  if (slot < 4)       { qt = slot;               j = 0;          P = 1; }
  else if (slot < 12) { int s = slot - 4;  qt = 4 + (s >> 1);  j = s & 1; P = 2; }
  else if (slot < 24) { int s = slot - 12; qt = 8 + s / 3;     j = s % 3; P = 3; }
  else                { int s = slot - 24; qt = 12 + (s >> 2); j = s & 3; P = 4; }

  const int t = threadIdx.x, w = t >> 6, lane = t & 63;
  const int lr = lane & 15, quad = lane >> 4;

  __shared__ unsigned short Ks[2 * 64 * 128];   // double-buffered, swizzled 16B chunks
  __shared__ unsigned short Vs[128 * 64];
  __shared__ unsigned short Ps[4][32 * PSTR];
  unsigned short* Ps16 = &Ps[w][0];

  const int row_base = qt * 128 + w * 32;

  bf16x8 qf[2][4];
  #pragma unroll
  for (int mt = 0; mt < 2; mt++)
    #pragma unroll
    for (int kk = 0; kk < 4; kk++)
      qf[mt][kk] = *(const bf16x8*)&Qb[((size_t)(b * SEQ + row_base + mt * 16 + lr)) * DMODEL
                                       + h * HD + kk * 32 + quad * 8];

  f32x4 o[2][8];
  #pragma unroll
  for (int mt = 0; mt < 2; mt++)
    #pragma unroll
    for (int nt = 0; nt < 8; nt++) o[mt][nt] = (f32x4){0.f, 0.f, 0.f, 0.f};
  float l_i[2][4];
  #pragma unroll
  for (int mt = 0; mt < 2; mt++)
    #pragma unroll
    for (int r = 0; r < 4; r++) l_i[mt][r] = 0.f;

  const int krow = t >> 4;
  const int vd = t >> 3, vc = (t & 7) ^ (vd & 7);
  const int ktend = 2 * qt + 2;

  #pragma unroll
  for (int jj = 0; jj < 4; jj++) {
    int row = krow + jj * 16;
    int c = (t & 15) ^ (row & 15);
    GLOAD_LDS16(&Kb[((size_t)(b * SEQ + j * 64 + row)) * DMODEL + h * HD + c * 8],
                &Ks[(t + jj * 256) * 8]);
  }
  #pragma unroll
  for (int jj = 0; jj < 4; jj++) {
    int d = vd + jj * 32;
    GLOAD_LDS16(&Vt[((size_t)((b * NH + h) * HD + d)) * SEQ + j * 64 + vc * 8],
                &Vs[(t + jj * 256) * 8]);
  }

  int kb = 0;
  for (int kt = j; kt < ktend; kt += P) {
    const bool more = (kt + P < ktend);
    const int kbase = kb * 8192;
    const int nkbase = 8192 - kbase;

    WAITVM(4);
    SBAR();

    f32x4 s4[2][4];
    #pragma unroll
    for (int mt = 0; mt < 2; mt++)
      #pragma unroll
      for (int nt = 0; nt < 4; nt++) s4[mt][nt] = (f32x4){0.f, 0.f, 0.f, 0.f};
    #pragma unroll
    for (int nt = 0; nt < 4; nt++)
      #pragma unroll
      for (int kk = 0; kk < 4; kk++) {
        bf16x8 bv = *(const bf16x8*)&Ks[kbase + ((nt * 16 + lr) * 16 + ((kk * 4 + quad) ^ lr)) * 8];
        s4[0][nt] = __builtin_amdgcn_mfma_f32_16x16x32_bf16(qf[0][kk], bv, s4[0][nt], 0, 0, 0);
        s4[1][nt] = __builtin_amdgcn_mfma_f32_16x16x32_bf16(qf[1][kk], bv, s4[1][nt], 0, 0, 0);
      }

    if (more) {
      #pragma unroll
      for (int jj = 0; jj < 4; jj++) {
        int row = krow + jj * 16;
        int c = (t & 15) ^ (row & 15);
        GLOAD_LDS16(&Kb[((size_t)(b * SEQ + (kt + P) * 64 + row)) * DMODEL + h * HD + c * 8],
                    &Ks[nkbase + (t + jj * 256) * 8]);
      }
    }

    const int maybe_mask = (kt * 64 + 63 > row_base);
    #pragma unroll
    for (int mt = 0; mt < 2; mt++) {
      #pragma unroll
      for (int nt = 0; nt < 4; nt++) s4[mt][nt] = s4[mt][nt] * SCALEL2;
      if (maybe_mask) {
        #pragma unroll
        for (int nt = 0; nt < 4; nt++) {
          int col = kt * 64 + nt * 16 + lr;
          #pragma unroll
          for (int r = 0; r < 4; r++)
            if (col > row_base + mt * 16 + quad * 4 + r) s4[mt][nt][r] = -__builtin_inff();
        }
      }
      #pragma unroll
      for (int nt = 0; nt < 4; nt++)
        #pragma unroll
        for (int r = 0; r < 4; r++) {
          float p = __builtin_amdgcn_exp2f(s4[mt][nt][r]);
          l_i[mt][r] += p;
          Ps[w][(mt * 16 + quad * 4 + r) * PSTR + nt * 16 + lr] = f2bf(p);
        }
    }

    if (more) WAITVM(4); else WAITVM(0);
    SBAR();

    #pragma unroll
    for (int kk2 = 0; kk2 < 2; kk2++) {
      bf16x8 af0 = *(const bf16x8*)&Ps[w][(lr) * PSTR + kk2 * 32 + quad * 8];
      bf16x8 af1 = *(const bf16x8*)&Ps[w][(16 + lr) * PSTR + kk2 * 32 + quad * 8];
      #pragma unroll
      for (int nt = 0; nt < 8; nt++) {
        bf16x8 bv = *(const bf16x8*)&Vs[((nt * 16 + lr) * 8 + ((kk2 * 4 + quad) ^ (lr & 7))) * 8];
        o[0][nt] = __builtin_amdgcn_mfma_f32_16x16x32_bf16(af0, bv, o[0][nt], 0, 0, 0);
        o[1][nt] = __builtin_amdgcn_mfma_f32_16x16x32_bf16(af1, bv, o[1][nt], 0, 0, 0);
      }
    }

    SBAR();
    if (more) {
      #pragma unroll
      for (int jj = 0; jj < 4; jj++) {
        int d = vd + jj * 32;
        GLOAD_LDS16(&Vt[((size_t)((b * NH + h) * HD + d)) * SEQ + (kt + P) * 64 + vc * 8],
                    &Vs[(t + jj * 256) * 8]);
      }
    }
    kb ^= 1;
  }

  #pragma unroll
  for (int mt = 0; mt < 2; mt++)
    #pragma unroll
    for (int r = 0; r < 4; r++) {
      float l = l_i[mt][r];
      #pragma unroll
      for (int off = 1; off < 16; off <<= 1) l += __shfl_xor(l, off, 64);
      l_i[mt][r] = l;
    }

  const size_t slotg = (size_t)(b * 16 + h) * 40 + slot;

  if (j == 0) {
    const float g = gate[h];
    #pragma unroll
    for (int mt = 0; mt < 2; mt++) {
      f32x4 as4 = (f32x4){0.f, 0.f, 0.f, 0.f};
      #pragma unroll
      for (int kk = 0; kk < 4; kk++) {
        bf16x8 akf = *(const bf16x8*)&AKb[(size_t)lr * DMODEL + h * HD + kk * 32 + quad * 8];
        as4 = __builtin_amdgcn_mfma_f32_16x16x32_bf16(qf[mt][kk], akf, as4, 0, 0, 0);
      }
      as4 = as4 * SCALEL2;
      float al[4];
      #pragma unroll
      for (int r = 0; r < 4; r++) {
        float p = (lr < NP) ? __builtin_amdgcn_exp2f(as4[r]) : 0.f;
        as4[r] = p;
        float sum = p;
        #pragma unroll
        for (int off = 1; off < 16; off <<= 1) sum += __shfl_xor(sum, off, 64);
        al[r] = sum;
      }
      #pragma unroll
      for (int r = 0; r < 4; r++) {
        Ps[w][(mt * 16 + quad * 4 + r) * PSTR + lr] = f2bf(as4[r]);
        Ps[w][(mt * 16 + quad * 4 + r) * PSTR + 16 + lr] = 0;
      }
      bf16x8 af = *(const bf16x8*)&Ps[w][(mt * 16 + lr) * PSTR + quad * 8];
      f32x4 pa[8];
      #pragma unroll
      for (int nt = 0; nt < 8; nt++) {
        bf16x8 bv = *(const bf16x8*)&avt[(size_t)(h * HD + nt * 16 + lr) * 32 + quad * 8];
        pa[nt] = __builtin_amdgcn_mfma_f32_16x16x32_bf16(af, bv, (f32x4){0.f, 0.f, 0.f, 0.f}, 0, 0, 0);
      }
      float invla[4];
      #pragma unroll
      for (int r = 0; r < 4; r++) invla[r] = g / al[r];
      #pragma unroll
      for (int nt = 0; nt < 8; nt++)
        #pragma unroll
        for (int r = 0; r < 4; r++)
          Ps16[(quad * 4 + r) * 128 + nt * 16 + lr] = f2bf(pa[nt][r] * invla[r]);
      size_t gb = (((size_t)(b * 16 + h) * 16 + qt)) * 16384 + (size_t)(w * 32 + mt * 16) * 128;
      #pragma unroll
      for (int it = 0; it < 4; it++) {
        int i = lane + it * 64;
        int rr = i >> 4, ch = i & 15;
        *(uint4*)&Aout[gb + rr * 128 + ch * 8] = *(const uint4*)&Ps16[rr * 128 + ch * 8];
      }
    }
  }

  #pragma unroll
  for (int mt = 0; mt < 2; mt++) {
    if (lr == 0) {
      #pragma unroll
      for (int r = 0; r < 4; r++) {
        int rl = w * 32 + mt * 16 + quad * 4 + r;
        ml[slotg * 128 + rl] = l_i[mt][r];
      }
    }
    #pragma unroll
    for (int nt = 0; nt < 8; nt++)
      #pragma unroll
      for (int r = 0; r < 4; r++)
        Ps16[(quad * 4 + r) * 128 + nt * 16 + lr] = f2bf(o[mt][nt][r]);
    size_t gb = slotg * 16384 + (size_t)(w * 32 + mt * 16) * 128;
    #pragma unroll
    for (int it = 0; it < 4; it++) {
      int i = lane + it * 64;
      int rr = i >> 4, ch = i & 15;
      *(uint4*)&Obuf[gb + rr * 128 + ch * 8] = *(const uint4*)&Ps16[rr * 128 + ch * 8];
    }
  }
}

// ---------- 8. merge split partials + adapter ----------
__global__ __launch_bounds__(256) void k_merge(const unsigned short* __restrict__ Obuf,
                                               const float* __restrict__ ml,
                                               const unsigned short* __restrict__ Aout,
                                               unsigned short* __restrict__ ab) {
  int idx = blockIdx.x * 256 + threadIdx.x;     // 2^20
  int ch = idx & 15;
  int row = (idx >> 4) & 2047;
  int h = (idx >> 15) & 15;
  int b = idx >> 19;
  int qt = row >> 7, rl = row & 127;
  int start = qt < 4 ? qt : qt < 8 ? 4 + 2 * (qt - 4) : qt < 12 ? 12 + 3 * (qt - 8) : 24 + 4 * (qt - 12);
  int P = qt < 4 ? 1 : qt < 8 ? 2 : qt < 12 ? 3 : 4;
  size_t sbase = (size_t)(b * 16 + h) * 40 + start;
  float den = 0.f;
  float acc[8] = {0.f, 0.f, 0.f, 0.f, 0.f, 0.f, 0.f, 0.f};
  #pragma unroll
  for (int jp = 0; jp < 4; jp++) {
    if (jp < P) {
      den += ml[(sbase + jp) * 128 + rl];
      uint4 ov = *(const uint4*)&Obuf[(sbase + jp) * 16384 + rl * 128 + ch * 8];
      const unsigned short* pv = (const unsigned short*)&ov;
      #pragma unroll
      for (int k = 0; k < 8; k++) acc[k] += bf2f(pv[k]);
    }
  }
  uint4 av = *(const uint4*)&Aout[(((size_t)(b * 16 + h) * 16 + qt)) * 16384 + rl * 128 + ch * 8];
  const unsigned short* pa = (const unsigned short*)&av;
  float dn = 1.0f / den;
  unsigned short res[8];
  #pragma unroll
  for (int k = 0; k < 8; k++) res[k] = f2bf(acc[k] * dn + bf2f(pa[k]));
  *(uint4*)&ab[((size_t)(b * 2048 + row)) * 2048 + h * 128 + ch * 8] = *(const uint4*)res;
}

// ---------- launcher ----------
extern "C" void kernel_launch(void* const* d_in, const int* in_sizes, int n_in,
                              void* d_out, int out_size, void* d_ws, size_t ws_size,
                              hipStream_t stream) {
  const float* hidden = (const float*)d_in[0];
  const float* Wq = (const float*)d_in[3];
  const float* Wk = (const float*)d_in[4];
  const float* Wv = (const float*)d_in[5];
  const float* Wo = (const float*)d_in[6];
  const float* Aq = (const float*)d_in[7];
  const float* gate = (const float*)d_in[8];
  float* out = (float*)d_out;

  char* ws = (char*)d_ws;
  size_t off = 0;
  auto alloc = [&](size_t bytes) -> void* {
    void* p = ws + off;
    off = (off + bytes + 255) & ~(size_t)255;
    return p;
  };
  unsigned short* wt   = (unsigned short*)alloc((size_t)4 * DMODEL * DMODEL * 2);
  unsigned short* xaug = (unsigned short*)alloc((size_t)(MAUG + 256) * DMODEL * 2);  // +pad: gemm stages past row 4105
  unsigned short* qb  = (unsigned short*)alloc((size_t)NB * SEQ * DMODEL * 2);
  unsigned short* kb  = (unsigned short*)alloc((size_t)NB * SEQ * DMODEL * 2);
  unsigned short* vt  = (unsigned short*)alloc((size_t)NB * SEQ * DMODEL * 2);
  unsigned short* akb = (unsigned short*)alloc((size_t)16 * DMODEL * 2);
  unsigned short* avt = (unsigned short*)alloc((size_t)DMODEL * 32 * 2);
  float* cost = (float*)alloc((size_t)SEQ * HD * 4);
  float* sint = (float*)alloc((size_t)SEQ * HD * 4);
  unsigned short* obuf = (unsigned short*)alloc((size_t)NB * NH * 40 * 16384 * 2);
  float* mlb = (float*)alloc((size_t)NB * NH * 40 * 128 * 4);
  unsigned short* aout = (unsigned short*)alloc((size_t)NB * NH * 16 * 16384 * 2);
  unsigned short* ab = xaug;   // reuse: xaug dead after k_gemmqkv

  k_prep<<<512 + 4096 + 4106, 256, 0, stream>>>(Wq, Wk, Wv, Wo, hidden, Aq, wt, xaug, cost, sint);
  k_gemmqkv<<<dim3(408), 512, 0, stream>>>(xaug, wt, cost, sint, qb, kb, vt, akb, avt);
  k_flash<<<dim3(640, 2), 256, 0, stream>>>(qb, kb, vt, akb, avt, gate, obuf, mlb, aout);
  k_merge<<<4096, 256, 0, stream>>>(obuf, mlb, aout, ab);
  k_gemmo<<<dim3(256), 512, 0, stream>>>(ab, wt + (size_t)3 * DMODEL * DMODEL, out);
}